// Round 16
// baseline (103.372 us; speedup 1.0000x reference)
//
#include <hip/hip_runtime.h>
#include <hip/hip_bf16.h>

typedef __bf16 bf16;
typedef __attribute__((ext_vector_type(4))) __bf16 bf16x4;
typedef __attribute__((ext_vector_type(8))) __bf16 bf16x8;
typedef __attribute__((ext_vector_type(4))) float f32x4;

#define GLD_LDS16(g, l)                                              \
  __builtin_amdgcn_global_load_lds(                                  \
      (const __attribute__((address_space(1))) void*)(g),            \
      (__attribute__((address_space(3))) void*)(l), 16, 0, 0)

// ---- prep: z<3 -> transpose+cast W[z] (K,N)->(N,K) bf16; z==3 -> cast x ----
__global__ void prep_kernel(const float* __restrict__ x,
                            const float* __restrict__ Wq,
                            const float* __restrict__ Wk,
                            const float* __restrict__ Wv,
                            bf16* __restrict__ xb, bf16* __restrict__ Wt) {
  __shared__ float tile[32][33];
  const int z = blockIdx.z;
  const int t = threadIdx.x;
  if (z < 3) {
    const float* W = (z == 0) ? Wq : ((z == 1) ? Wk : Wv);
    bf16* out = Wt + (size_t)z * 1024 * 1024;
    const int k0 = blockIdx.x * 32, n0 = blockIdx.y * 32;
    const int r = t >> 3, c = (t & 7) * 4;
    float4 v = *reinterpret_cast<const float4*>(&W[(size_t)(k0 + r) * 1024 + n0 + c]);
    tile[r][c + 0] = v.x; tile[r][c + 1] = v.y;
    tile[r][c + 2] = v.z; tile[r][c + 3] = v.w;
    __syncthreads();
    bf16x4 o;
    o[0] = (bf16)tile[c + 0][r]; o[1] = (bf16)tile[c + 1][r];
    o[2] = (bf16)tile[c + 2][r]; o[3] = (bf16)tile[c + 3][r];
    *reinterpret_cast<bf16x4*>(&out[(size_t)(n0 + r) * 1024 + k0 + c]) = o;
  } else {
    const int tid = (blockIdx.y * 32 + blockIdx.x) * 256 + t;
#pragma unroll
    for (int i = 0; i < 8; ++i) {
      const int idx = tid + i * 262144;
      float4 v = reinterpret_cast<const float4*>(x)[idx];
      bf16x4 o;
      o[0] = (bf16)v.x; o[1] = (bf16)v.y; o[2] = (bf16)v.z; o[3] = (bf16)v.w;
      reinterpret_cast<bf16x4*>(xb)[idx] = o;
    }
  }
}

// --------- fused QKV GEMM: C[8192][3072] = x @ Wt^T + bias ----------------
// R15 (best GEMM: 57.5 us, MfmaUtil ~37%): 8-phase, BM=256 BN=192 BK=64,
// grid 32x16 = 512 = exactly 2 rounds; 8 waves 4Mx2N; 12 MFMA/phase;
// vmcnt(4) @P0/P1/P2, none @P3; tail 4/2/0. FROZEN this round.
__global__ __launch_bounds__(512, 2) void qkv_gemm_kernel(
    const bf16* __restrict__ xb, const bf16* __restrict__ Wt,
    const float* __restrict__ bq, const float* __restrict__ bk,
    const float* __restrict__ bv, bf16* __restrict__ QKV) {
  __shared__ bf16 ldsA[2][256 * 64];  // 64 KB
  __shared__ bf16 ldsB[2][192 * 64];  // 48 KB

  const int n0g = blockIdx.x * 192;  // may cross q/k/v boundaries
  const int m0 = blockIdx.y * 256;

  const int t = threadIdx.x;
  const int lane = t & 63, wid = t >> 6;
  const int wm = wid >> 1, wn = wid & 1;
  const int l15 = lane & 15, kg = lane >> 4;

  const int trow = t >> 3;
  const int csrc = (((t & 7) * 16) ^ ((trow & 7) << 4)) >> 1;

  auto stA = [&](int h, int c, int kt, int wb) {
    GLD_LDS16(xb + (size_t)(m0 + h * 128 + c * 64 + trow) * 1024 + kt + csrc,
              &ldsA[wb][h * 8192 + c * 4096 + t * 8]);
  };
  auto stB = [&](int h, int c, int kt, int wb) {
    GLD_LDS16(Wt + (size_t)(n0g + h * 96 + c * 32 + trow) * 1024 + kt + csrc,
              &ldsB[wb][h * 6144 + c * 2048 + t * 8]);
  };
#define STAGE_A(H, KT, WB) { stA(H, 0, KT, WB); stA(H, 1, KT, WB); }
#define STAGE_B(H, KT, WB) { stB(H, 0, KT, WB); stB(H, 1, KT, WB); }

  auto readA = [&](int rb, int ah, int mi, int ks) {
    const int row = wm * 32 + mi * 16 + l15;
    const int colb = (ks * 64 + kg * 16) ^ ((l15 & 7) << 4);
    return *reinterpret_cast<const bf16x8*>(
        &ldsA[rb][ah * 8192 + row * 64 + (colb >> 1)]);
  };
  auto readB = [&](int rb, int bh, int ni, int ks) {
    const int row = wn * 48 + ni * 16 + l15;
    const int colb = (ks * 64 + kg * 16) ^ ((l15 & 7) << 4);
    return *reinterpret_cast<const bf16x8*>(
        &ldsB[rb][bh * 6144 + row * 64 + (colb >> 1)]);
  };

  f32x4 acc[2][2][2][3];
#pragma unroll
  for (int a = 0; a < 2; ++a)
#pragma unroll
    for (int b = 0; b < 2; ++b)
#pragma unroll
      for (int i = 0; i < 2; ++i)
#pragma unroll
        for (int j = 0; j < 3; ++j) {
          f32x4 zz = {0.f, 0.f, 0.f, 0.f};
          acc[a][b][i][j] = zz;
        }

  bf16x8 af[2][2], bf0[3][2], bf1[3][2];

#define MFMA12(AH, BH, BF)                                                     \
    _Pragma("unroll")                                                          \
    for (int mi = 0; mi < 2; ++mi)                                             \
      _Pragma("unroll")                                                        \
      for (int ni = 0; ni < 3; ++ni) {                                         \
        acc[AH][BH][mi][ni] = __builtin_amdgcn_mfma_f32_16x16x32_bf16(         \
            af[mi][0], BF[ni][0], acc[AH][BH][mi][ni], 0, 0, 0);               \
        acc[AH][BH][mi][ni] = __builtin_amdgcn_mfma_f32_16x16x32_bf16(         \
            af[mi][1], BF[ni][1], acc[AH][BH][mi][ni], 0, 0, 0);               \
      }

#define PHASE0(RB, WB, KST, DO_STAGE, WN)                                      \
  {                                                                            \
    asm volatile("s_waitcnt vmcnt(" #WN ")" ::: "memory");                     \
    __builtin_amdgcn_s_barrier();                                              \
    __builtin_amdgcn_sched_barrier(0);                                         \
    _Pragma("unroll")                                                          \
    for (int mi = 0; mi < 2; ++mi)                                             \
      _Pragma("unroll")                                                        \
      for (int ks = 0; ks < 2; ++ks) af[mi][ks] = readA(RB, 0, mi, ks);        \
    _Pragma("unroll")                                                          \
    for (int ni = 0; ni < 3; ++ni)                                             \
      _Pragma("unroll")                                                        \
      for (int ks = 0; ks < 2; ++ks) bf0[ni][ks] = readB(RB, 0, ni, ks);       \
    __builtin_amdgcn_sched_barrier(0);                                         \
    if (DO_STAGE) STAGE_A(0, KST, WB);                                         \
    asm volatile("s_waitcnt lgkmcnt(0)" ::: "memory");                         \
    __builtin_amdgcn_sched_barrier(0);                                         \
    __builtin_amdgcn_s_setprio(1);                                             \
    MFMA12(0, 0, bf0)                                                          \
    __builtin_amdgcn_s_setprio(0);                                             \
  }

#define PHASE1(RB, WB, KST, DO_STAGE, WN)                                      \
  {                                                                            \
    asm volatile("s_waitcnt vmcnt(" #WN ")" ::: "memory");                     \
    __builtin_amdgcn_s_barrier();                                              \
    __builtin_amdgcn_sched_barrier(0);                                         \
    _Pragma("unroll")                                                          \
    for (int ni = 0; ni < 3; ++ni)                                             \
      _Pragma("unroll")                                                        \
      for (int ks = 0; ks < 2; ++ks) bf1[ni][ks] = readB(RB, 1, ni, ks);       \
    __builtin_amdgcn_sched_barrier(0);                                         \
    if (DO_STAGE) STAGE_B(0, KST, WB);                                         \
    asm volatile("s_waitcnt lgkmcnt(0)" ::: "memory");                         \
    __builtin_amdgcn_sched_barrier(0);                                         \
    __builtin_amdgcn_s_setprio(1);                                             \
    MFMA12(0, 1, bf1)                                                          \
    __builtin_amdgcn_s_setprio(0);                                             \
  }

#define PHASE2(RB, WB, KST, DO_STAGE, WN)                                      \
  {                                                                            \
    asm volatile("s_waitcnt vmcnt(" #WN ")" ::: "memory");                     \
    __builtin_amdgcn_s_barrier();                                              \
    __builtin_amdgcn_sched_barrier(0);                                         \
    _Pragma("unroll")                                                          \
    for (int mi = 0; mi < 2; ++mi)                                             \
      _Pragma("unroll")                                                        \
      for (int ks = 0; ks < 2; ++ks) af[mi][ks] = readA(RB, 1, mi, ks);        \
    __builtin_amdgcn_sched_barrier(0);                                         \
    if (DO_STAGE) STAGE_B(1, KST, WB);                                         \
    asm volatile("s_waitcnt lgkmcnt(0)" ::: "memory");                         \
    __builtin_amdgcn_sched_barrier(0);                                         \
    __builtin_amdgcn_s_setprio(1);                                             \
    MFMA12(1, 1, bf1)                                                          \
    __builtin_amdgcn_s_setprio(0);                                             \
  }

#define PHASE3(RB, WB, KST, DO_STAGE)                                          \
  {                                                                            \
    if (DO_STAGE) STAGE_A(1, KST, WB);                                         \
    __builtin_amdgcn_s_setprio(1);                                             \
    MFMA12(1, 0, bf0)                                                          \
    __builtin_amdgcn_s_setprio(0);                                             \
  }

#define KTILE(RB, WB, KST, DO_STAGE)                                           \
  PHASE0(RB, WB, KST, DO_STAGE, 4)                                             \
  PHASE1(RB, WB, KST, DO_STAGE, 4)                                             \
  PHASE2(RB, WB, KST, DO_STAGE, 4)                                             \
  PHASE3(RB, WB, KST, DO_STAGE)

  STAGE_A(0, 0, 0) STAGE_B(0, 0, 0) STAGE_B(1, 0, 0) STAGE_A(1, 0, 0)

  for (int tp = 0; tp < 7; ++tp) {
    const int kb = tp * 128;
    KTILE(0, 1, kb + 64, 1)
    KTILE(1, 0, kb + 128, 1)
  }
  KTILE(0, 1, 960, 1)
  PHASE0(1, 0, 0, 0, 4)
  PHASE1(1, 0, 0, 0, 2)
  PHASE2(1, 0, 0, 0, 0)
  PHASE3(1, 0, 0, 0)
#undef KTILE
#undef PHASE0
#undef PHASE1
#undef PHASE2
#undef PHASE3
#undef MFMA12
#undef STAGE_A
#undef STAGE_B

  const int rowb = kg * 4;
#pragma unroll
  for (int ah = 0; ah < 2; ++ah)
#pragma unroll
    for (int bh = 0; bh < 2; ++bh)
#pragma unroll
      for (int ni = 0; ni < 3; ++ni) {
        const int col = n0g + bh * 96 + wn * 48 + ni * 16 + l15;
        const int cz = col & 1023;
        const float bv_ =
            (col < 1024) ? bq[cz] : ((col < 2048) ? bk[cz] : bv[cz]);
#pragma unroll
        for (int mi = 0; mi < 2; ++mi) {
          const int row = m0 + ah * 128 + wm * 32 + mi * 16 + rowb;
#pragma unroll
          for (int j = 0; j < 4; ++j)
            QKV[(size_t)(row + j) * 3072 + col] =
                (bf16)(acc[ah][bh][mi][ni][j] + bv_);
        }
      }
}

// ------- local attention, window +-2; 4 positions per wave ----------------
// Wave handles p0..p0+3. Window rows s0-2..s0+5 (8) loaded ONCE, transient
// (phase K: dot-accumulate then discard; phase V: weight-accumulate then
// discard). 20 dots, one interleaved shuffle-reduce, 4 softmaxes.
__global__ void local_attn_kernel(const bf16* __restrict__ QKV,
                                  float* __restrict__ out) {
  const int t = threadIdx.x;
  const int lane = t & 63, wid = t >> 6;
  const int p0 = (blockIdx.x * 4 + wid) * 4;  // 4 consecutive positions
  const int s0 = p0 & 2047;
  const size_t hoff = (size_t)lane * 16;

  // Q rows p0..p0+3 -> f32
  float qf[4][16];
#pragma unroll
  for (int q = 0; q < 4; ++q) {
    const bf16* qp = QKV + (size_t)(p0 + q) * 3072 + hoff;
    bf16x8 a0 = *reinterpret_cast<const bf16x8*>(qp);
    bf16x8 a1 = *reinterpret_cast<const bf16x8*>(qp + 8);
#pragma unroll
    for (int j = 0; j < 8; ++j) {
      qf[q][j] = (float)a0[j];
      qf[q][8 + j] = (float)a1[j];
    }
  }

  bool val[8];
#pragma unroll
  for (int r = 0; r < 8; ++r) {
    const int sr = s0 - 2 + r;
    val[r] = (sr >= 0) && (sr < 2048);
  }

  // ---- phase K: 20 dots, K rows transient ----
  float d[4][5];
#pragma unroll
  for (int q = 0; q < 4; ++q)
#pragma unroll
    for (int w = 0; w < 5; ++w) d[q][w] = 0.f;

#pragma unroll
  for (int r = 0; r < 8; ++r) {
    if (!val[r]) continue;  // wave-uniform
    const bf16* kp = QKV + (size_t)(p0 - 2 + r) * 3072 + 1024 + hoff;
    bf16x8 k0 = *reinterpret_cast<const bf16x8*>(kp);
    bf16x8 k1 = *reinterpret_cast<const bf16x8*>(kp + 8);
    float kf[16];
#pragma unroll
    for (int j = 0; j < 8; ++j) { kf[j] = (float)k0[j]; kf[8 + j] = (float)k1[j]; }
#pragma unroll
    for (int q = 0; q < 4; ++q) {
      if (r < q || r > q + 4) continue;  // compile-time prune
      float a = 0.f;
#pragma unroll
      for (int j = 0; j < 16; ++j) a += qf[q][j] * kf[j];
      d[q][r - q] = a;
    }
  }

  // interleaved butterfly reduce of all 20 partial dots
#pragma unroll
  for (int off = 32; off >= 1; off >>= 1) {
#pragma unroll
    for (int q = 0; q < 4; ++q)
#pragma unroll
      for (int w = 0; w < 5; ++w) d[q][w] += __shfl_xor(d[q][w], off, 64);
  }

  // ---- 4 softmaxes ----
  const float NEG = -__builtin_inff();
  float p[4][5];
#pragma unroll
  for (int q = 0; q < 4; ++q) {
    float sc[5];
#pragma unroll
    for (int w = 0; w < 5; ++w)
      sc[w] = val[q + w] ? d[q][w] * (1.0f / 32.0f) : NEG;
    float m_ = NEG;
#pragma unroll
    for (int w = 0; w < 5; ++w) m_ = fmaxf(m_, sc[w]);
    float su = 0.f;
#pragma unroll
    for (int w = 0; w < 5; ++w) { p[q][w] = __expf(sc[w] - m_); su += p[q][w]; }
    const float inv = 1.0f / su;
#pragma unroll
    for (int w = 0; w < 5; ++w) p[q][w] *= inv;
  }

  // ---- phase V: V rows transient, accumulate outputs ----
  float of[4][16];
#pragma unroll
  for (int q = 0; q < 4; ++q)
#pragma unroll
    for (int j = 0; j < 16; ++j) of[q][j] = 0.f;

#pragma unroll
  for (int r = 0; r < 8; ++r) {
    if (!val[r]) continue;
    const bf16* vp = QKV + (size_t)(p0 - 2 + r) * 3072 + 2048 + hoff;
    bf16x8 v0 = *reinterpret_cast<const bf16x8*>(vp);
    bf16x8 v1 = *reinterpret_cast<const bf16x8*>(vp + 8);
    float vf[16];
#pragma unroll
    for (int j = 0; j < 8; ++j) { vf[j] = (float)v0[j]; vf[8 + j] = (float)v1[j]; }
#pragma unroll
    for (int q = 0; q < 4; ++q) {
      if (r < q || r > q + 4) continue;
      const float pw = p[q][r - q];
#pragma unroll
      for (int j = 0; j < 16; ++j) of[q][j] += pw * vf[j];
    }
  }

#pragma unroll
  for (int q = 0; q < 4; ++q) {
    float* op = out + (size_t)(p0 + q) * 1024 + hoff;
#pragma unroll
    for (int j4 = 0; j4 < 4; ++j4) {
      f32x4 o = {of[q][4 * j4], of[q][4 * j4 + 1], of[q][4 * j4 + 2],
                 of[q][4 * j4 + 3]};
      *reinterpret_cast<f32x4*>(op + 4 * j4) = o;
    }
  }
}

extern "C" void kernel_launch(void* const* d_in, const int* in_sizes, int n_in,
                              void* d_out, int out_size, void* d_ws,
                              size_t ws_size, hipStream_t stream) {
  const float* x  = (const float*)d_in[0];
  const float* Wq = (const float*)d_in[1];
  const float* bq = (const float*)d_in[2];
  const float* Wk = (const float*)d_in[3];
  const float* bk = (const float*)d_in[4];
  const float* Wv = (const float*)d_in[5];
  const float* bv = (const float*)d_in[6];

  char* ws = (char*)d_ws;
  bf16* xb  = (bf16*)ws;                       // 16 MB: x as bf16
  bf16* Wt  = (bf16*)(ws + (size_t)16777216);  // 6 MB: [3072][1024] W^T bf16
  bf16* QKV = (bf16*)(ws + (size_t)23068672);  // 48 MB: fused [8192][3072]
  float* outf = (float*)d_out;

  prep_kernel<<<dim3(32, 32, 4), 256, 0, stream>>>(x, Wq, Wk, Wv, xb, Wt);
  qkv_gemm_kernel<<<dim3(16, 32), 512, 0, stream>>>(xb, Wt, bq, bk, bv, QKV);
  local_attn_kernel<<<512, 256, 0, stream>>>(QKV, outf);
}

// Round 17
// 94.929 us; speedup vs baseline: 1.0889x; 1.0889x over previous
//
#include <hip/hip_runtime.h>
#include <hip/hip_bf16.h>

typedef __bf16 bf16;
typedef __attribute__((ext_vector_type(4))) __bf16 bf16x4;
typedef __attribute__((ext_vector_type(8))) __bf16 bf16x8;
typedef __attribute__((ext_vector_type(4))) float f32x4;

#define GLD_LDS16(g, l)                                              \
  __builtin_amdgcn_global_load_lds(                                  \
      (const __attribute__((address_space(1))) void*)(g),            \
      (__attribute__((address_space(3))) void*)(l), 16, 0, 0)

// ---- prep: z<3 -> transpose+cast W[z] (K,N)->(N,K) bf16; z==3 -> cast x ----
__global__ void prep_kernel(const float* __restrict__ x,
                            const float* __restrict__ Wq,
                            const float* __restrict__ Wk,
                            const float* __restrict__ Wv,
                            bf16* __restrict__ xb, bf16* __restrict__ Wt) {
  __shared__ float tile[32][33];
  const int z = blockIdx.z;
  const int t = threadIdx.x;
  if (z < 3) {
    const float* W = (z == 0) ? Wq : ((z == 1) ? Wk : Wv);
    bf16* out = Wt + (size_t)z * 1024 * 1024;
    const int k0 = blockIdx.x * 32, n0 = blockIdx.y * 32;
    const int r = t >> 3, c = (t & 7) * 4;
    float4 v = *reinterpret_cast<const float4*>(&W[(size_t)(k0 + r) * 1024 + n0 + c]);
    tile[r][c + 0] = v.x; tile[r][c + 1] = v.y;
    tile[r][c + 2] = v.z; tile[r][c + 3] = v.w;
    __syncthreads();
    bf16x4 o;
    o[0] = (bf16)tile[c + 0][r]; o[1] = (bf16)tile[c + 1][r];
    o[2] = (bf16)tile[c + 2][r]; o[3] = (bf16)tile[c + 3][r];
    *reinterpret_cast<bf16x4*>(&out[(size_t)(n0 + r) * 1024 + k0 + c]) = o;
  } else {
    const int tid = (blockIdx.y * 32 + blockIdx.x) * 256 + t;
#pragma unroll
    for (int i = 0; i < 8; ++i) {
      const int idx = tid + i * 262144;
      float4 v = reinterpret_cast<const float4*>(x)[idx];
      bf16x4 o;
      o[0] = (bf16)v.x; o[1] = (bf16)v.y; o[2] = (bf16)v.z; o[3] = (bf16)v.w;
      reinterpret_cast<bf16x4*>(xb)[idx] = o;
    }
  }
}

// --------- fused QKV GEMM: C[8192][3072] = x @ Wt^T + bias ----------------
// R15 (best GEMM: 57.5 us): 8-phase, BM=256 BN=192 BK=64, grid 32x16 = 512
// = exactly 2 rounds; 8 waves 4Mx2N; 12 MFMA/phase; vmcnt(4) @P0/P1/P2,
// none @P3; tail 4/2/0. FROZEN.
__global__ __launch_bounds__(512, 2) void qkv_gemm_kernel(
    const bf16* __restrict__ xb, const bf16* __restrict__ Wt,
    const float* __restrict__ bq, const float* __restrict__ bk,
    const float* __restrict__ bv, bf16* __restrict__ QKV) {
  __shared__ bf16 ldsA[2][256 * 64];  // 64 KB
  __shared__ bf16 ldsB[2][192 * 64];  // 48 KB

  const int n0g = blockIdx.x * 192;  // may cross q/k/v boundaries
  const int m0 = blockIdx.y * 256;

  const int t = threadIdx.x;
  const int lane = t & 63, wid = t >> 6;
  const int wm = wid >> 1, wn = wid & 1;
  const int l15 = lane & 15, kg = lane >> 4;

  const int trow = t >> 3;
  const int csrc = (((t & 7) * 16) ^ ((trow & 7) << 4)) >> 1;

  auto stA = [&](int h, int c, int kt, int wb) {
    GLD_LDS16(xb + (size_t)(m0 + h * 128 + c * 64 + trow) * 1024 + kt + csrc,
              &ldsA[wb][h * 8192 + c * 4096 + t * 8]);
  };
  auto stB = [&](int h, int c, int kt, int wb) {
    GLD_LDS16(Wt + (size_t)(n0g + h * 96 + c * 32 + trow) * 1024 + kt + csrc,
              &ldsB[wb][h * 6144 + c * 2048 + t * 8]);
  };
#define STAGE_A(H, KT, WB) { stA(H, 0, KT, WB); stA(H, 1, KT, WB); }
#define STAGE_B(H, KT, WB) { stB(H, 0, KT, WB); stB(H, 1, KT, WB); }

  auto readA = [&](int rb, int ah, int mi, int ks) {
    const int row = wm * 32 + mi * 16 + l15;
    const int colb = (ks * 64 + kg * 16) ^ ((l15 & 7) << 4);
    return *reinterpret_cast<const bf16x8*>(
        &ldsA[rb][ah * 8192 + row * 64 + (colb >> 1)]);
  };
  auto readB = [&](int rb, int bh, int ni, int ks) {
    const int row = wn * 48 + ni * 16 + l15;
    const int colb = (ks * 64 + kg * 16) ^ ((l15 & 7) << 4);
    return *reinterpret_cast<const bf16x8*>(
        &ldsB[rb][bh * 6144 + row * 64 + (colb >> 1)]);
  };

  f32x4 acc[2][2][2][3];
#pragma unroll
  for (int a = 0; a < 2; ++a)
#pragma unroll
    for (int b = 0; b < 2; ++b)
#pragma unroll
      for (int i = 0; i < 2; ++i)
#pragma unroll
        for (int j = 0; j < 3; ++j) {
          f32x4 zz = {0.f, 0.f, 0.f, 0.f};
          acc[a][b][i][j] = zz;
        }

  bf16x8 af[2][2], bf0[3][2], bf1[3][2];

#define MFMA12(AH, BH, BF)                                                     \
    _Pragma("unroll")                                                          \
    for (int mi = 0; mi < 2; ++mi)                                             \
      _Pragma("unroll")                                                        \
      for (int ni = 0; ni < 3; ++ni) {                                         \
        acc[AH][BH][mi][ni] = __builtin_amdgcn_mfma_f32_16x16x32_bf16(         \
            af[mi][0], BF[ni][0], acc[AH][BH][mi][ni], 0, 0, 0);               \
        acc[AH][BH][mi][ni] = __builtin_amdgcn_mfma_f32_16x16x32_bf16(         \
            af[mi][1], BF[ni][1], acc[AH][BH][mi][ni], 0, 0, 0);               \
      }

#define PHASE0(RB, WB, KST, DO_STAGE, WN)                                      \
  {                                                                            \
    asm volatile("s_waitcnt vmcnt(" #WN ")" ::: "memory");                     \
    __builtin_amdgcn_s_barrier();                                              \
    __builtin_amdgcn_sched_barrier(0);                                         \
    _Pragma("unroll")                                                          \
    for (int mi = 0; mi < 2; ++mi)                                             \
      _Pragma("unroll")                                                        \
      for (int ks = 0; ks < 2; ++ks) af[mi][ks] = readA(RB, 0, mi, ks);        \
    _Pragma("unroll")                                                          \
    for (int ni = 0; ni < 3; ++ni)                                             \
      _Pragma("unroll")                                                        \
      for (int ks = 0; ks < 2; ++ks) bf0[ni][ks] = readB(RB, 0, ni, ks);       \
    __builtin_amdgcn_sched_barrier(0);                                         \
    if (DO_STAGE) STAGE_A(0, KST, WB);                                         \
    asm volatile("s_waitcnt lgkmcnt(0)" ::: "memory");                         \
    __builtin_amdgcn_sched_barrier(0);                                         \
    __builtin_amdgcn_s_setprio(1);                                             \
    MFMA12(0, 0, bf0)                                                          \
    __builtin_amdgcn_s_setprio(0);                                             \
  }

#define PHASE1(RB, WB, KST, DO_STAGE, WN)                                      \
  {                                                                            \
    asm volatile("s_waitcnt vmcnt(" #WN ")" ::: "memory");                     \
    __builtin_amdgcn_s_barrier();                                              \
    __builtin_amdgcn_sched_barrier(0);                                         \
    _Pragma("unroll")                                                          \
    for (int ni = 0; ni < 3; ++ni)                                             \
      _Pragma("unroll")                                                        \
      for (int ks = 0; ks < 2; ++ks) bf1[ni][ks] = readB(RB, 1, ni, ks);       \
    __builtin_amdgcn_sched_barrier(0);                                         \
    if (DO_STAGE) STAGE_B(0, KST, WB);                                         \
    asm volatile("s_waitcnt lgkmcnt(0)" ::: "memory");                         \
    __builtin_amdgcn_sched_barrier(0);                                         \
    __builtin_amdgcn_s_setprio(1);                                             \
    MFMA12(0, 1, bf1)                                                          \
    __builtin_amdgcn_s_setprio(0);                                             \
  }

#define PHASE2(RB, WB, KST, DO_STAGE, WN)                                      \
  {                                                                            \
    asm volatile("s_waitcnt vmcnt(" #WN ")" ::: "memory");                     \
    __builtin_amdgcn_s_barrier();                                              \
    __builtin_amdgcn_sched_barrier(0);                                         \
    _Pragma("unroll")                                                          \
    for (int mi = 0; mi < 2; ++mi)                                             \
      _Pragma("unroll")                                                        \
      for (int ks = 0; ks < 2; ++ks) af[mi][ks] = readA(RB, 1, mi, ks);        \
    __builtin_amdgcn_sched_barrier(0);                                         \
    if (DO_STAGE) STAGE_B(1, KST, WB);                                         \
    asm volatile("s_waitcnt lgkmcnt(0)" ::: "memory");                         \
    __builtin_amdgcn_sched_barrier(0);                                         \
    __builtin_amdgcn_s_setprio(1);                                             \
    MFMA12(1, 1, bf1)                                                          \
    __builtin_amdgcn_s_setprio(0);                                             \
  }

#define PHASE3(RB, WB, KST, DO_STAGE)                                          \
  {                                                                            \
    if (DO_STAGE) STAGE_A(1, KST, WB);                                         \
    __builtin_amdgcn_s_setprio(1);                                             \
    MFMA12(1, 0, bf0)                                                          \
    __builtin_amdgcn_s_setprio(0);                                             \
  }

#define KTILE(RB, WB, KST, DO_STAGE)                                           \
  PHASE0(RB, WB, KST, DO_STAGE, 4)                                             \
  PHASE1(RB, WB, KST, DO_STAGE, 4)                                             \
  PHASE2(RB, WB, KST, DO_STAGE, 4)                                             \
  PHASE3(RB, WB, KST, DO_STAGE)

  STAGE_A(0, 0, 0) STAGE_B(0, 0, 0) STAGE_B(1, 0, 0) STAGE_A(1, 0, 0)

  for (int tp = 0; tp < 7; ++tp) {
    const int kb = tp * 128;
    KTILE(0, 1, kb + 64, 1)
    KTILE(1, 0, kb + 128, 1)
  }
  KTILE(0, 1, 960, 1)
  PHASE0(1, 0, 0, 0, 4)
  PHASE1(1, 0, 0, 0, 2)
  PHASE2(1, 0, 0, 0, 0)
  PHASE3(1, 0, 0, 0)
#undef KTILE
#undef PHASE0
#undef PHASE1
#undef PHASE2
#undef PHASE3
#undef MFMA12
#undef STAGE_A
#undef STAGE_B

  const int rowb = kg * 4;
#pragma unroll
  for (int ah = 0; ah < 2; ++ah)
#pragma unroll
    for (int bh = 0; bh < 2; ++bh)
#pragma unroll
      for (int ni = 0; ni < 3; ++ni) {
        const int col = n0g + bh * 96 + wn * 48 + ni * 16 + l15;
        const int cz = col & 1023;
        const float bv_ =
            (col < 1024) ? bq[cz] : ((col < 2048) ? bk[cz] : bv[cz]);
#pragma unroll
        for (int mi = 0; mi < 2; ++mi) {
          const int row = m0 + ah * 128 + wm * 32 + mi * 16 + rowb;
#pragma unroll
          for (int j = 0; j < 4; ++j)
            QKV[(size_t)(row + j) * 3072 + col] =
                (bf16)(acc[ah][bh][mi][ni][j] + bv_);
        }
      }
}

// ------- local attention, window +-2; 2 positions per wave ----------------
// Transient K-phase then V-phase (low VGPR -> 4 waves/SIMD); Q pre-scaled
// by 1/sqrt(H); bijective XCD-chunk block swizzle for K/V L2 locality.
__global__ __launch_bounds__(256, 4) void local_attn_kernel(
    const bf16* __restrict__ QKV, float* __restrict__ out) {
  const int t = threadIdx.x;
  const int lane = t & 63, wid = t >> 6;
  // 1024 blocks, 8 XCDs -> XCD c owns blocks c*128..c*128+127 (contiguous
  // positions) after swizzle; bijective since 1024 % 8 == 0.
  const int nb = (blockIdx.x & 7) * 128 + (blockIdx.x >> 3);
  const int p0 = nb * 8 + wid * 2;  // even
  const int s0 = p0 & 2047;
  const size_t hoff = (size_t)lane * 16;

  // Q rows p0, p0+1, pre-scaled by 1/32 = 1/sqrt(1024)
  float q0f[16], q1f[16];
  {
    const bf16* qp = QKV + (size_t)p0 * 3072 + hoff;
    bf16x8 a0 = *reinterpret_cast<const bf16x8*>(qp);
    bf16x8 a1 = *reinterpret_cast<const bf16x8*>(qp + 8);
    bf16x8 b0 = *reinterpret_cast<const bf16x8*>(qp + 3072);
    bf16x8 b1 = *reinterpret_cast<const bf16x8*>(qp + 3072 + 8);
#pragma unroll
    for (int j = 0; j < 8; ++j) {
      q0f[j] = (float)a0[j] * (1.0f / 32.0f);
      q0f[8 + j] = (float)a1[j] * (1.0f / 32.0f);
      q1f[j] = (float)b0[j] * (1.0f / 32.0f);
      q1f[8 + j] = (float)b1[j] * (1.0f / 32.0f);
    }
  }

  bool val[6];
#pragma unroll
  for (int r = 0; r < 6; ++r) {
    const int sr = s0 - 2 + r;
    val[r] = (sr >= 0) && (sr < 2048);
  }

  // ---- phase K: rows transient; 10 dots ----
  float d0[5], d1[5];
#pragma unroll
  for (int w = 0; w < 5; ++w) { d0[w] = 0.f; d1[w] = 0.f; }
#pragma unroll
  for (int r = 0; r < 6; ++r) {
    if (!val[r]) continue;  // wave-uniform
    const bf16* kp = QKV + (size_t)(p0 - 2 + r) * 3072 + 1024 + hoff;
    bf16x8 k0 = *reinterpret_cast<const bf16x8*>(kp);
    bf16x8 k1 = *reinterpret_cast<const bf16x8*>(kp + 8);
    float kf[16];
#pragma unroll
    for (int j = 0; j < 8; ++j) { kf[j] = (float)k0[j]; kf[8 + j] = (float)k1[j]; }
    if (r < 5) {  // q0 x rows 0..4
      float a = 0.f;
#pragma unroll
      for (int j = 0; j < 16; ++j) a += q0f[j] * kf[j];
      d0[r] = a;
    }
    if (r > 0) {  // q1 x rows 1..5
      float b = 0.f;
#pragma unroll
      for (int j = 0; j < 16; ++j) b += q1f[j] * kf[j];
      d1[r - 1] = b;
    }
  }
#pragma unroll
  for (int off = 32; off >= 1; off >>= 1) {
#pragma unroll
    for (int w = 0; w < 5; ++w) {
      d0[w] += __shfl_xor(d0[w], off, 64);
      d1[w] += __shfl_xor(d1[w], off, 64);
    }
  }

  // ---- dual softmax (scores already scaled) ----
  const float NEG = -__builtin_inff();
  float p0w[5], p1w[5];
  {
    float sc0[5], sc1[5];
#pragma unroll
    for (int w = 0; w < 5; ++w) {
      sc0[w] = val[w] ? d0[w] : NEG;
      sc1[w] = val[w + 1] ? d1[w] : NEG;
    }
    float m0_ = NEG, m1_ = NEG;
#pragma unroll
    for (int w = 0; w < 5; ++w) { m0_ = fmaxf(m0_, sc0[w]); m1_ = fmaxf(m1_, sc1[w]); }
    float su0 = 0.f, su1 = 0.f;
#pragma unroll
    for (int w = 0; w < 5; ++w) {
      p0w[w] = __expf(sc0[w] - m0_); su0 += p0w[w];
      p1w[w] = __expf(sc1[w] - m1_); su1 += p1w[w];
    }
    const float i0 = 1.0f / su0, i1 = 1.0f / su1;
#pragma unroll
    for (int w = 0; w < 5; ++w) { p0w[w] *= i0; p1w[w] *= i1; }
  }

  // ---- phase V: rows transient; weighted accumulate ----
  float of0[16], of1[16];
#pragma unroll
  for (int j = 0; j < 16; ++j) { of0[j] = 0.f; of1[j] = 0.f; }
#pragma unroll
  for (int r = 0; r < 6; ++r) {
    if (!val[r]) continue;
    const bf16* vp = QKV + (size_t)(p0 - 2 + r) * 3072 + 2048 + hoff;
    bf16x8 v0 = *reinterpret_cast<const bf16x8*>(vp);
    bf16x8 v1 = *reinterpret_cast<const bf16x8*>(vp + 8);
    float vf[16];
#pragma unroll
    for (int j = 0; j < 8; ++j) { vf[j] = (float)v0[j]; vf[8 + j] = (float)v1[j]; }
    if (r < 5) {
      const float pw = p0w[r];
#pragma unroll
      for (int j = 0; j < 16; ++j) of0[j] += pw * vf[j];
    }
    if (r > 0) {
      const float pw = p1w[r - 1];
#pragma unroll
      for (int j = 0; j < 16; ++j) of1[j] += pw * vf[j];
    }
  }

  float* op0 = out + (size_t)p0 * 1024 + hoff;
  float* op1 = op0 + 1024;
#pragma unroll
  for (int j4 = 0; j4 < 4; ++j4) {
    f32x4 o0 = {of0[4 * j4], of0[4 * j4 + 1], of0[4 * j4 + 2], of0[4 * j4 + 3]};
    f32x4 o1 = {of1[4 * j4], of1[4 * j4 + 1], of1[4 * j4 + 2], of1[4 * j4 + 3]};
    *reinterpret_cast<f32x4*>(op0 + 4 * j4) = o0;
    *reinterpret_cast<f32x4*>(op1 + 4 * j4) = o1;
  }
}

extern "C" void kernel_launch(void* const* d_in, const int* in_sizes, int n_in,
                              void* d_out, int out_size, void* d_ws,
                              size_t ws_size, hipStream_t stream) {
  const float* x  = (const float*)d_in[0];
  const float* Wq = (const float*)d_in[1];
  const float* bq = (const float*)d_in[2];
  const float* Wk = (const float*)d_in[3];
  const float* bk = (const float*)d_in[4];
  const float* Wv = (const float*)d_in[5];
  const float* bv = (const float*)d_in[6];

  char* ws = (char*)d_ws;
  bf16* xb  = (bf16*)ws;                       // 16 MB: x as bf16
  bf16* Wt  = (bf16*)(ws + (size_t)16777216);  // 6 MB: [3072][1024] W^T bf16
  bf16* QKV = (bf16*)(ws + (size_t)23068672);  // 48 MB: fused [8192][3072]
  float* outf = (float*)d_out;

  prep_kernel<<<dim3(32, 32, 4), 256, 0, stream>>>(x, Wq, Wk, Wv, xb, Wt);
  qkv_gemm_kernel<<<dim3(16, 32), 512, 0, stream>>>(xb, Wt, bq, bk, bv, QKV);
  local_attn_kernel<<<1024, 256, 0, stream>>>(QKV, outf);
}